// Round 19
// baseline (124.293 us; speedup 1.0000x reference)
//
#include <hip/hip_runtime.h>
#include <hip/hip_bf16.h>

typedef float f32x4 __attribute__((ext_vector_type(4)));
typedef short s16x4 __attribute__((ext_vector_type(4)));
typedef unsigned int u32;
typedef unsigned short u16;
typedef unsigned int u32x2 __attribute__((ext_vector_type(2)));
typedef unsigned int u32x4 __attribute__((ext_vector_type(4)));
typedef unsigned short u16x4 __attribute__((ext_vector_type(4)));
typedef unsigned short u16x8 __attribute__((ext_vector_type(8)));

#define MFMA16(a, b, c) __builtin_amdgcn_mfma_f32_16x16x16bf16_1k((a), (b), (c), 0, 0, 0)

// q pre-scale folds 1/sqrt(dk) AND log2(e): softmax done in base-2 (v_exp_f32 = 2^x)
#define QSCALE 0.18033688f

__device__ __forceinline__ void mfma32(f32x4& acc, u16x8 a, u16x8 b) {
  asm("v_mfma_f32_16x16x32_bf16 %0, %1, %2, %0" : "+v"(acc) : "v"(a), "v"(b));
}

__device__ __forceinline__ void gload16(const u16* g, u16* l) {
  __builtin_amdgcn_global_load_lds((const __attribute__((address_space(1))) void*)g,
                                   (__attribute__((address_space(3))) void*)l, 16, 0, 0);
}

__device__ __forceinline__ u16 f2bf(float f) {
  u32 u = __builtin_bit_cast(u32, f);
  u += 0x7fffu + ((u >> 16) & 1u);
  return (u16)(u >> 16);
}

// v_cvt_pk_bf16_f32: D.lo = bf16(S0), D.hi = bf16(S1)
__device__ __forceinline__ u32 pk2(float lo, float hi) {
  u32 d;
  asm("v_cvt_pk_bf16_f32 %0, %1, %2" : "=v"(d) : "v"(lo), "v"(hi));
  return d;
}

__device__ __forceinline__ float ex2(float x) {
  float r;
  asm("v_exp_f32 %0, %1" : "=v"(r) : "v"(x));
  return r;
}

// ---- pre-convert kernels ----
__global__ __launch_bounds__(256) void convX(const float* __restrict__ Q, const float* __restrict__ K,
                                             const float* __restrict__ V, u16* __restrict__ o) {
  const int z = blockIdx.y;
  const float* s = z == 0 ? Q : (z == 1 ? K : V);
  const size_t i = ((size_t)blockIdx.x * 256 + threadIdx.x) * 4;
  float4 v4 = *(const float4*)&s[i];
  u16x4 ob = { f2bf(v4.x), f2bf(v4.y), f2bf(v4.z), f2bf(v4.w) };
  *(u16x4*)&o[(size_t)z * 4194304 + i] = ob;
}

__global__ __launch_bounds__(256) void convW(const float* __restrict__ WQ, const float* __restrict__ WK,
                                             const float* __restrict__ WV, u16* __restrict__ o) {
  const int z = blockIdx.z;
  const float* W = z == 0 ? WQ : (z == 1 ? WK : WV);
  const int k0 = blockIdx.x * 8, n = blockIdx.y * 256 + threadIdx.x;
  u16x8 ob;
  #pragma unroll
  for (int j = 0; j < 8; ++j) ob[j] = f2bf(W[(size_t)(k0 + j) * 1024 + n]);
  *(u16x8*)&o[(size_t)z * 1048576 + (size_t)n * 1024 + k0] = ob;
}

// ---- proj: bf16 inputs, BK=64, gload_lds + T2 swizzle + T1 XCD block swizzle ----
__global__ __launch_bounds__(256) void proj_fast(
    const u16* __restrict__ Xb, const u16* __restrict__ Wt,
    const float* __restrict__ bQ, const float* __restrict__ bV, u16* __restrict__ Y0) {
  const int z = blockIdx.z;
  const u16* X = Xb + (size_t)z * 4194304;
  const u16* W = Wt + (size_t)z * 1048576;
  u16* Y = Y0 + (size_t)z * 4194304;
  const float* bias = (z == 0) ? bQ : (z == 1) ? nullptr : bV;
  const float scale = (z == 0) ? QSCALE : 1.0f;

  __shared__ u16 Alds[128][64];   // linear rows (gload_lds dest); XOR-swizzled chunks
  __shared__ u16 Blds[128][64];

  const int tid = threadIdx.x;
  const int w = tid >> 6, ln = tid & 63, g = ln >> 4, q16 = ln & 15;
  const int x7 = q16 & 7;
  const int wr = w >> 1, wc = w & 1;

  // T1 XCD swizzle: phys p -> virt v = (p%8)*32 + p/8; each XCD gets 4 row-panels x 8 col-blocks
  const int p = blockIdx.x + 8 * blockIdx.y;
  const int v = ((p & 7) << 5) | (p >> 3);
  const int rowbase = (v >> 3) * 128, cbase = (v & 7) * 128;

  const int srow = w * 8 + (ln >> 3);
  const int sch = (ln & 7) ^ ((ln >> 3) & 7);
  const u16* Xg = X + (size_t)(rowbase + srow) * 1024 + sch * 8;
  const u16* Wg = W + (size_t)(cbase + srow) * 1024 + sch * 8;
  u16* Abase = &Alds[0][0] + w * 512;
  u16* Bbase = &Blds[0][0] + w * 512;

  f32x4 acc[4][4] = {};

  for (int k0 = 0; k0 < 1024; k0 += 64) {
    #pragma unroll
    for (int pp = 0; pp < 4; ++pp) {
      gload16(Xg + (size_t)pp * 32768 + k0, Abase + pp * 2048);
      gload16(Wg + (size_t)pp * 32768 + k0, Bbase + pp * 2048);
    }
    __syncthreads();

    u16x8 af[4][2], bfr[4][2];
    #pragma unroll
    for (int mi = 0; mi < 4; ++mi)
      #pragma unroll
      for (int ks = 0; ks < 2; ++ks)
        af[mi][ks] = *(const u16x8*)&Alds[wr * 64 + mi * 16 + q16][((ks * 4 + g) ^ x7) * 8];
    #pragma unroll
    for (int ni = 0; ni < 4; ++ni)
      #pragma unroll
      for (int ks = 0; ks < 2; ++ks)
        bfr[ni][ks] = *(const u16x8*)&Blds[wc * 64 + ni * 16 + q16][((ks * 4 + g) ^ x7) * 8];

    #pragma unroll
    for (int mi = 0; mi < 4; ++mi)
      #pragma unroll
      for (int ni = 0; ni < 4; ++ni) {
        mfma32(acc[mi][ni], af[mi][0], bfr[ni][0]);
        mfma32(acc[mi][ni], af[mi][1], bfr[ni][1]);
      }
    __syncthreads();
  }

  #pragma unroll
  for (int ni = 0; ni < 4; ++ni) {
    const int c = cbase + wc * 64 + ni * 16 + q16;
    const float bi = bias ? bias[c] : 0.0f;
    const int hh = c >> 6, d = c & 63;
    #pragma unroll
    for (int mi = 0; mi < 4; ++mi)
      #pragma unroll
      for (int r = 0; r < 4; ++r) {
        const int grow = rowbase + wr * 64 + mi * 16 + g * 4 + r;
        const int bb = grow >> 11, l = grow & 2047;
        const float val = (acc[mi][ni][r] + bi) * scale;
        const size_t idx = (z == 2)
            ? (((size_t)(bb * 16 + hh)) * 64 + d) * 2048 + l     // V stored transposed [bh][d][l]
            : (((size_t)(bb * 16 + hh)) * 2048 + l) * 64 + d;
        Y[idx] = f2bf(val);
      }
  }
}

// ---- legacy proj fallback ----
__global__ __launch_bounds__(256) void proj_legacy(
    const float* __restrict__ Qin, const float* __restrict__ Kin, const float* __restrict__ Vin,
    const float* __restrict__ WQ, const float* __restrict__ WK, const float* __restrict__ WV,
    const float* __restrict__ bQ, const float* __restrict__ bV,
    u16* __restrict__ ws) {
  const int z = blockIdx.z;
  const float* X = (z == 0) ? Qin : (z == 1) ? Kin : Vin;
  const float* W = (z == 0) ? WQ : (z == 1) ? WK : WV;
  const float* bias = (z == 0) ? bQ : (z == 1) ? nullptr : bV;
  u16* Y = ws + (size_t)z * 4194304;
  const float scale = (z == 0) ? QSCALE : 1.0f;

  __shared__ u16 Alds[128][40];
  __shared__ u16 Blds[128][40];

  const int tid = threadIdx.x;
  const int w = tid >> 6, ln = tid & 63, g = ln >> 4, q16 = ln & 15;
  const int wr = w >> 1, wc = w & 1;
  const int rowbase = blockIdx.y * 128, cbase = blockIdx.x * 128;

  f32x4 acc[4][4] = {};

  for (int k0 = 0; k0 < 1024; k0 += 32) {
    #pragma unroll
    for (int i = 0; i < 4; ++i) {
      int idx = tid + i * 256;
      int row = idx >> 3, kq = idx & 7;
      const float4 a = *(const float4*)&X[(size_t)(rowbase + row) * 1024 + k0 + kq * 4];
      u16x4 pk = { f2bf(a.x), f2bf(a.y), f2bf(a.z), f2bf(a.w) };
      *(u16x4*)&Alds[row][kq * 4] = pk;
    }
    #pragma unroll
    for (int i = 0; i < 4; ++i) {
      int idx = tid + i * 256;
      int kk = idx >> 5, nq = idx & 31;
      const float4 wv = *(const float4*)&W[(size_t)(k0 + kk) * 1024 + cbase + nq * 4];
      Blds[nq * 4 + 0][kk] = f2bf(wv.x);
      Blds[nq * 4 + 1][kk] = f2bf(wv.y);
      Blds[nq * 4 + 2][kk] = f2bf(wv.z);
      Blds[nq * 4 + 3][kk] = f2bf(wv.w);
    }
    __syncthreads();

    s16x4 af[4][2], bfr[4][2];
    #pragma unroll
    for (int mi = 0; mi < 4; ++mi)
      #pragma unroll
      for (int s = 0; s < 2; ++s)
        af[mi][s] = *(const s16x4*)&Alds[wr * 64 + mi * 16 + q16][s * 16 + g * 4];
    #pragma unroll
    for (int ni = 0; ni < 4; ++ni)
      #pragma unroll
      for (int s = 0; s < 2; ++s)
        bfr[ni][s] = *(const s16x4*)&Blds[wc * 64 + ni * 16 + q16][s * 16 + g * 4];

    #pragma unroll
    for (int mi = 0; mi < 4; ++mi)
      #pragma unroll
      for (int ni = 0; ni < 4; ++ni) {
        acc[mi][ni] = MFMA16(af[mi][0], bfr[ni][0], acc[mi][ni]);
        acc[mi][ni] = MFMA16(af[mi][1], bfr[ni][1], acc[mi][ni]);
      }
    __syncthreads();
  }

  #pragma unroll
  for (int ni = 0; ni < 4; ++ni) {
    const int c = cbase + wc * 64 + ni * 16 + q16;
    const float bi = bias ? bias[c] : 0.0f;
    const int hh = c >> 6, d = c & 63;
    #pragma unroll
    for (int mi = 0; mi < 4; ++mi)
      #pragma unroll
      for (int r = 0; r < 4; ++r) {
        const int grow = rowbase + wr * 64 + mi * 16 + g * 4 + r;
        const int bb = grow >> 11, l = grow & 2047;
        const float val = (acc[mi][ni][r] + bi) * scale;
        const size_t idx = (z == 2)
            ? (((size_t)(bb * 16 + hh)) * 64 + d) * 2048 + l
            : (((size_t)(bb * 16 + hh)) * 2048 + l) * 64 + d;
        Y[idx] = f2bf(val);
      }
  }
}

// ---- flash attention: round-16 core + time-shared pt (25.6KB LDS -> 6 blocks/CU) ----
__global__ __launch_bounds__(256) void attn_kernel(
    const u16* __restrict__ ws, const int* __restrict__ mask,
    float* __restrict__ out, float* __restrict__ part1, float* __restrict__ pl) {
  __shared__ u16 klds[4096];     // [key][chunk^(key&7)] 64x64
  __shared__ u16 vtlds[4096];    // [d][chunk^(d&7)] 64x64 (V^T)
  __shared__ u16 pt[4][16][72];  // per-wave P^T, TIME-SHARED across u; 144B rows (b128-safe)

  const int bh = blockIdx.y, b = bh >> 4, h = bh & 15;
  const int qbase = blockIdx.x * 128;
  const int half = blockIdx.z;
  const int koff = half << 10;
  float* po = half ? part1 : out;
  float* plh = pl + half * 65536;   // [half][bh][2048]

  const u16* qp = ws + (size_t)bh * 131072;
  const u16* kp = ws + 4194304 + (size_t)bh * 131072;
  const u16* vp = ws + 8388608 + (size_t)bh * 131072;  // [64 d][2048 l]
  const int* maskrow = mask + (h & 1) * 2048;          // torch-tile quirk: batch idx = h%2

  const int tid = threadIdx.x;
  const int w = tid >> 6, ln = tid & 63, g = ln >> 4, q16 = ln & 15;
  const int x7 = q16 & 7;

  // Q as B-operand: 2 q-frags per wave (wave covers 32 q-rows)
  u16x8 qf[2][2];
  #pragma unroll
  for (int u = 0; u < 2; ++u)
    #pragma unroll
    for (int s = 0; s < 2; ++s)
      qf[u][s] = *(const u16x8*)(qp + (size_t)(qbase + w * 32 + u * 16 + q16) * 64 + s * 32 + g * 8);

  const int srow = w * 8 + (ln >> 3);
  const int sch = (ln & 7) ^ (ln >> 3);
  const u16* kg = kp + (size_t)srow * 64 + sch * 8;
  const u16* vg = vp + (size_t)srow * 2048 + sch * 8;

  float l_[2] = { 0.f, 0.f };   // per-lane per-u PARTIAL denominators
  f32x4 ov[2][4] = {};          // O^T partials

  for (int kt = koff; kt < koff + 1024; kt += 64) {
    __syncthreads();
    gload16(kg + (size_t)kt * 64, klds + w * 512);
    gload16(kg + (size_t)kt * 64 + 2048, klds + w * 512 + 2048);
    gload16(vg + kt, vtlds + w * 512);
    gload16(vg + kt + 65536, vtlds + w * 512 + 2048);
    const unsigned long long bal = __ballot(maskrow[kt + ln] != 0);
    __syncthreads();

    f32x4 sf[2][4];
    #pragma unroll
    for (int f = 0; f < 4; ++f) {
      u16x8 kf0 = *(const u16x8*)&klds[(f * 16 + q16) * 64 + (g ^ x7) * 8];
      u16x8 kf1 = *(const u16x8*)&klds[(f * 16 + q16) * 64 + ((4 + g) ^ x7) * 8];
      #pragma unroll
      for (int u = 0; u < 2; ++u) {
        f32x4 s = { 0.f, 0.f, 0.f, 0.f };
        mfma32(s, kf0, qf[u][0]);
        mfma32(s, kf1, qf[u][1]);
        sf[u][f] = s;
      }
    }
    {
      const u32 blo = (u32)bal, bhi = (u32)(bal >> 32);
      #pragma unroll
      for (int f = 0; f < 4; ++f) {
        const u32 nib = (((f & 2) ? bhi : blo) >> (16 * (f & 1) + 4 * g)) & 15u;
        #pragma unroll
        for (int r2 = 0; r2 < 4; ++r2)
          if (!((nib >> r2) & 1u)) { sf[0][f][r2] = -1e9f; sf[1][f][r2] = -1e9f; }
      }
    }

    // no-max softmax: p = 2^(S'); masked -> exact 0; l accumulates linearly
    #pragma unroll
    for (int u = 0; u < 2; ++u) {
      #pragma unroll
      for (int f = 0; f < 4; ++f)
        #pragma unroll
        for (int r2 = 0; r2 < 4; ++r2)
          sf[u][f][r2] = ex2(sf[u][f][r2]);
      l_[u] += ((sf[u][0][0] + sf[u][0][1]) + (sf[u][0][2] + sf[u][0][3])) +
               ((sf[u][1][0] + sf[u][1][1]) + (sf[u][1][2] + sf[u][1][3])) +
               ((sf[u][2][0] + sf[u][2][1]) + (sf[u][2][2] + sf[u][2][3])) +
               ((sf[u][3][0] + sf[u][3][1]) + (sf[u][3][2] + sf[u][3][3]));
    }

    // P^T roundtrip, pt TIME-SHARED: phase u=0 then u=1 (in-wave DS is in-order; fences pin compiler)
    u16x8 pa0[2], pa1[2];
    #pragma unroll
    for (int u = 0; u < 2; ++u) {
      #pragma unroll
      for (int f = 0; f < 4; ++f) {
        u32x2 pw = { pk2(sf[u][f][0], sf[u][f][1]), pk2(sf[u][f][2], sf[u][f][3]) };
        *(u16x4*)&pt[w][q16][f * 16 + 4 * g] = __builtin_bit_cast(u16x4, pw);
      }
      asm volatile("s_waitcnt lgkmcnt(0)" ::: "memory");
      pa0[u] = *(const u16x8*)&pt[w][q16][g * 8];
      pa1[u] = *(const u16x8*)&pt[w][q16][32 + g * 8];
      asm volatile("" ::: "memory");   // pin reads above next phase's writes
    }

    // O^T += V^T @ P : vf fragments shared across both u (the DS amortization)
    #pragma unroll
    for (int dc = 0; dc < 4; ++dc) {
      u16x8 vf0 = *(const u16x8*)&vtlds[(dc * 16 + q16) * 64 + (g ^ x7) * 8];
      u16x8 vf1 = *(const u16x8*)&vtlds[(dc * 16 + q16) * 64 + ((4 + g) ^ x7) * 8];
      #pragma unroll
      for (int u = 0; u < 2; ++u) {
        mfma32(ov[u][dc], vf0, pa0[u]);
        mfma32(ov[u][dc], vf1, pa1[u]);
      }
    }
  }

  // epilogue: reduce partial l_ per u; store UN-normalized partials
  #pragma unroll
  for (int u = 0; u < 2; ++u) {
    l_[u] += __shfl_xor(l_[u], 16);
    l_[u] += __shfl_xor(l_[u], 32);
    const int qrow = qbase + w * 32 + u * 16 + q16;
    if ((ln & 48) == 0) plh[bh * 2048 + qrow] = l_[u];
    #pragma unroll
    for (int dc = 0; dc < 4; ++dc) {
      float4 o4 = { ov[u][dc][0], ov[u][dc][1], ov[u][dc][2], ov[u][dc][3] };
      *(float4*)&po[((size_t)(b * 2048 + qrow)) * 1024 + h * 64 + dc * 16 + 4 * g] = o4;
    }
  }
}

// ---- combine: out = (out + part1) / (l0 + l1), elementwise float4 ----
__global__ __launch_bounds__(256) void combine_kernel(
    float* __restrict__ out, const float* __restrict__ part1, const float* __restrict__ pl) {
  const int e = blockIdx.x * 256 + threadIdx.x;   // float4 index
  const int i = e * 4;
  const int b = i >> 21;            // / (2048*1024)
  const int rem = i & 2097151;
  const int q = rem >> 10;
  const int c = rem & 1023;
  const int h = c >> 6;
  const int bhq = ((b * 16 + h) << 11) + q;
  const float rinv = 1.0f / (pl[bhq] + pl[65536 + bhq]);
  float4 a = *(const float4*)&out[i];
  float4 p = *(const float4*)&part1[i];
  float4 r = { (a.x + p.x) * rinv, (a.y + p.y) * rinv, (a.z + p.z) * rinv, (a.w + p.w) * rinv };
  *(float4*)&out[i] = r;
}

extern "C" void kernel_launch(void* const* d_in, const int* in_sizes, int n_in,
                              void* d_out, int out_size, void* d_ws, size_t ws_size,
                              hipStream_t stream) {
  const float* Qin = (const float*)d_in[0];
  const float* Kin = (const float*)d_in[1];
  const float* Vin = (const float*)d_in[2];
  const int* mask = (const int*)d_in[3];
  const float* WQ = (const float*)d_in[4];
  const float* bQ = (const float*)d_in[5];
  const float* WK = (const float*)d_in[6];
  const float* WV = (const float*)d_in[7];
  const float* bV = (const float*)d_in[8];
  float* out = (float*)d_out;
  u16* ws = (u16*)d_ws;

  // ws layout (u16): [0) qkv 3x4194304 | [12582912) Xb (reused as part1+pl after proj) | [25165824) Wt
  float* part1 = (float*)(ws + 12582912);             // 16.7 MB
  float* pl = (float*)(ws + 12582912 + 8388608);      // 0.5 MB

  const bool fast = ws_size >= (size_t)56623104;
  if (fast) {
    convX<<<dim3(4096, 3), 256, 0, stream>>>(Qin, Kin, Vin, ws + 12582912);
    convW<<<dim3(128, 4, 3), 256, 0, stream>>>(WQ, WK, WV, ws + 25165824);
    proj_fast<<<dim3(8, 32, 3), 256, 0, stream>>>(ws + 12582912, ws + 25165824, bQ, bV, ws);
  } else {
    proj_legacy<<<dim3(8, 32, 3), 256, 0, stream>>>(Qin, Kin, Vin, WQ, WK, WV, bQ, bV, ws);
  }
  attn_kernel<<<dim3(16, 32, 2), 256, 0, stream>>>(ws, mask, out, part1, pl);
  combine_kernel<<<4096, 256, 0, stream>>>(out, part1, pl);
}

// Round 20
// 117.820 us; speedup vs baseline: 1.0549x; 1.0549x over previous
//
#include <hip/hip_runtime.h>
#include <hip/hip_bf16.h>

typedef float f32x4 __attribute__((ext_vector_type(4)));
typedef short s16x4 __attribute__((ext_vector_type(4)));
typedef unsigned int u32;
typedef unsigned short u16;
typedef unsigned int u32x2 __attribute__((ext_vector_type(2)));
typedef unsigned int u32x4 __attribute__((ext_vector_type(4)));
typedef unsigned short u16x4 __attribute__((ext_vector_type(4)));
typedef unsigned short u16x8 __attribute__((ext_vector_type(8)));

#define MFMA16(a, b, c) __builtin_amdgcn_mfma_f32_16x16x16bf16_1k((a), (b), (c), 0, 0, 0)

// q pre-scale folds 1/sqrt(dk) AND log2(e): softmax done in base-2 (v_exp_f32 = 2^x)
#define QSCALE 0.18033688f

__device__ __forceinline__ void mfma32(f32x4& acc, u16x8 a, u16x8 b) {
  asm("v_mfma_f32_16x16x32_bf16 %0, %1, %2, %0" : "+v"(acc) : "v"(a), "v"(b));
}

__device__ __forceinline__ void gload16(const u16* g, u16* l) {
  __builtin_amdgcn_global_load_lds((const __attribute__((address_space(1))) void*)g,
                                   (__attribute__((address_space(3))) void*)l, 16, 0, 0);
}

__device__ __forceinline__ u16 f2bf(float f) {
  u32 u = __builtin_bit_cast(u32, f);
  u += 0x7fffu + ((u >> 16) & 1u);
  return (u16)(u >> 16);
}

// v_cvt_pk_bf16_f32: D.lo = bf16(S0), D.hi = bf16(S1)
__device__ __forceinline__ u32 pk2(float lo, float hi) {
  u32 d;
  asm("v_cvt_pk_bf16_f32 %0, %1, %2" : "=v"(d) : "v"(lo), "v"(hi));
  return d;
}

__device__ __forceinline__ float ex2(float x) {
  float r;
  asm("v_exp_f32 %0, %1" : "=v"(r) : "v"(x));
  return r;
}

// ---- pre-convert kernels ----
__global__ __launch_bounds__(256) void convX(const float* __restrict__ Q, const float* __restrict__ K,
                                             const float* __restrict__ V, u16* __restrict__ o) {
  const int z = blockIdx.y;
  const float* s = z == 0 ? Q : (z == 1 ? K : V);
  const size_t i = ((size_t)blockIdx.x * 256 + threadIdx.x) * 4;
  float4 v4 = *(const float4*)&s[i];
  u16x4 ob = { f2bf(v4.x), f2bf(v4.y), f2bf(v4.z), f2bf(v4.w) };
  *(u16x4*)&o[(size_t)z * 4194304 + i] = ob;
}

__global__ __launch_bounds__(256) void convW(const float* __restrict__ WQ, const float* __restrict__ WK,
                                             const float* __restrict__ WV, u16* __restrict__ o) {
  const int z = blockIdx.z;
  const float* W = z == 0 ? WQ : (z == 1 ? WK : WV);
  const int k0 = blockIdx.x * 8, n = blockIdx.y * 256 + threadIdx.x;
  u16x8 ob;
  #pragma unroll
  for (int j = 0; j < 8; ++j) ob[j] = f2bf(W[(size_t)(k0 + j) * 1024 + n]);
  *(u16x8*)&o[(size_t)z * 1048576 + (size_t)n * 1024 + k0] = ob;
}

// ---- proj: bf16 inputs, BK=64, gload_lds + T2 swizzle + T1 XCD block swizzle ----
__global__ __launch_bounds__(256) void proj_fast(
    const u16* __restrict__ Xb, const u16* __restrict__ Wt,
    const float* __restrict__ bQ, const float* __restrict__ bV, u16* __restrict__ Y0) {
  const int z = blockIdx.z;
  const u16* X = Xb + (size_t)z * 4194304;
  const u16* W = Wt + (size_t)z * 1048576;
  u16* Y = Y0 + (size_t)z * 4194304;
  const float* bias = (z == 0) ? bQ : (z == 1) ? nullptr : bV;
  const float scale = (z == 0) ? QSCALE : 1.0f;

  __shared__ u16 Alds[128][64];   // linear rows (gload_lds dest); XOR-swizzled chunks
  __shared__ u16 Blds[128][64];

  const int tid = threadIdx.x;
  const int w = tid >> 6, ln = tid & 63, g = ln >> 4, q16 = ln & 15;
  const int x7 = q16 & 7;
  const int wr = w >> 1, wc = w & 1;

  // T1 XCD swizzle: phys p -> virt v = (p%8)*32 + p/8; each XCD gets 4 row-panels x 8 col-blocks
  const int p = blockIdx.x + 8 * blockIdx.y;
  const int v = ((p & 7) << 5) | (p >> 3);
  const int rowbase = (v >> 3) * 128, cbase = (v & 7) * 128;

  const int srow = w * 8 + (ln >> 3);
  const int sch = (ln & 7) ^ ((ln >> 3) & 7);
  const u16* Xg = X + (size_t)(rowbase + srow) * 1024 + sch * 8;
  const u16* Wg = W + (size_t)(cbase + srow) * 1024 + sch * 8;
  u16* Abase = &Alds[0][0] + w * 512;
  u16* Bbase = &Blds[0][0] + w * 512;

  f32x4 acc[4][4] = {};

  for (int k0 = 0; k0 < 1024; k0 += 64) {
    #pragma unroll
    for (int pp = 0; pp < 4; ++pp) {
      gload16(Xg + (size_t)pp * 32768 + k0, Abase + pp * 2048);
      gload16(Wg + (size_t)pp * 32768 + k0, Bbase + pp * 2048);
    }
    __syncthreads();

    u16x8 af[4][2], bfr[4][2];
    #pragma unroll
    for (int mi = 0; mi < 4; ++mi)
      #pragma unroll
      for (int ks = 0; ks < 2; ++ks)
        af[mi][ks] = *(const u16x8*)&Alds[wr * 64 + mi * 16 + q16][((ks * 4 + g) ^ x7) * 8];
    #pragma unroll
    for (int ni = 0; ni < 4; ++ni)
      #pragma unroll
      for (int ks = 0; ks < 2; ++ks)
        bfr[ni][ks] = *(const u16x8*)&Blds[wc * 64 + ni * 16 + q16][((ks * 4 + g) ^ x7) * 8];

    #pragma unroll
    for (int mi = 0; mi < 4; ++mi)
      #pragma unroll
      for (int ni = 0; ni < 4; ++ni) {
        mfma32(acc[mi][ni], af[mi][0], bfr[ni][0]);
        mfma32(acc[mi][ni], af[mi][1], bfr[ni][1]);
      }
    __syncthreads();
  }

  #pragma unroll
  for (int ni = 0; ni < 4; ++ni) {
    const int c = cbase + wc * 64 + ni * 16 + q16;
    const float bi = bias ? bias[c] : 0.0f;
    const int hh = c >> 6, d = c & 63;
    #pragma unroll
    for (int mi = 0; mi < 4; ++mi)
      #pragma unroll
      for (int r = 0; r < 4; ++r) {
        const int grow = rowbase + wr * 64 + mi * 16 + g * 4 + r;
        const int bb = grow >> 11, l = grow & 2047;
        const float val = (acc[mi][ni][r] + bi) * scale;
        const size_t idx = (z == 2)
            ? (((size_t)(bb * 16 + hh)) * 64 + d) * 2048 + l     // V stored transposed [bh][d][l]
            : (((size_t)(bb * 16 + hh)) * 2048 + l) * 64 + d;
        Y[idx] = f2bf(val);
      }
  }
}

// ---- legacy proj fallback ----
__global__ __launch_bounds__(256) void proj_legacy(
    const float* __restrict__ Qin, const float* __restrict__ Kin, const float* __restrict__ Vin,
    const float* __restrict__ WQ, const float* __restrict__ WK, const float* __restrict__ WV,
    const float* __restrict__ bQ, const float* __restrict__ bV,
    u16* __restrict__ ws) {
  const int z = blockIdx.z;
  const float* X = (z == 0) ? Qin : (z == 1) ? Kin : Vin;
  const float* W = (z == 0) ? WQ : (z == 1) ? WK : WV;
  const float* bias = (z == 0) ? bQ : (z == 1) ? nullptr : bV;
  u16* Y = ws + (size_t)z * 4194304;
  const float scale = (z == 0) ? QSCALE : 1.0f;

  __shared__ u16 Alds[128][40];
  __shared__ u16 Blds[128][40];

  const int tid = threadIdx.x;
  const int w = tid >> 6, ln = tid & 63, g = ln >> 4, q16 = ln & 15;
  const int wr = w >> 1, wc = w & 1;
  const int rowbase = blockIdx.y * 128, cbase = blockIdx.x * 128;

  f32x4 acc[4][4] = {};

  for (int k0 = 0; k0 < 1024; k0 += 32) {
    #pragma unroll
    for (int i = 0; i < 4; ++i) {
      int idx = tid + i * 256;
      int row = idx >> 3, kq = idx & 7;
      const float4 a = *(const float4*)&X[(size_t)(rowbase + row) * 1024 + k0 + kq * 4];
      u16x4 pk = { f2bf(a.x), f2bf(a.y), f2bf(a.z), f2bf(a.w) };
      *(u16x4*)&Alds[row][kq * 4] = pk;
    }
    #pragma unroll
    for (int i = 0; i < 4; ++i) {
      int idx = tid + i * 256;
      int kk = idx >> 5, nq = idx & 31;
      const float4 wv = *(const float4*)&W[(size_t)(k0 + kk) * 1024 + cbase + nq * 4];
      Blds[nq * 4 + 0][kk] = f2bf(wv.x);
      Blds[nq * 4 + 1][kk] = f2bf(wv.y);
      Blds[nq * 4 + 2][kk] = f2bf(wv.z);
      Blds[nq * 4 + 3][kk] = f2bf(wv.w);
    }
    __syncthreads();

    s16x4 af[4][2], bfr[4][2];
    #pragma unroll
    for (int mi = 0; mi < 4; ++mi)
      #pragma unroll
      for (int s = 0; s < 2; ++s)
        af[mi][s] = *(const s16x4*)&Alds[wr * 64 + mi * 16 + q16][s * 16 + g * 4];
    #pragma unroll
    for (int ni = 0; ni < 4; ++ni)
      #pragma unroll
      for (int s = 0; s < 2; ++s)
        bfr[ni][s] = *(const s16x4*)&Blds[wc * 64 + ni * 16 + q16][s * 16 + g * 4];

    #pragma unroll
    for (int mi = 0; mi < 4; ++mi)
      #pragma unroll
      for (int ni = 0; ni < 4; ++ni) {
        acc[mi][ni] = MFMA16(af[mi][0], bfr[ni][0], acc[mi][ni]);
        acc[mi][ni] = MFMA16(af[mi][1], bfr[ni][1], acc[mi][ni]);
      }
    __syncthreads();
  }

  #pragma unroll
  for (int ni = 0; ni < 4; ++ni) {
    const int c = cbase + wc * 64 + ni * 16 + q16;
    const float bi = bias ? bias[c] : 0.0f;
    const int hh = c >> 6, d = c & 63;
    #pragma unroll
    for (int mi = 0; mi < 4; ++mi)
      #pragma unroll
      for (int r = 0; r < 4; ++r) {
        const int grow = rowbase + wr * 64 + mi * 16 + g * 4 + r;
        const int bb = grow >> 11, l = grow & 2047;
        const float val = (acc[mi][ni][r] + bi) * scale;
        const size_t idx = (z == 2)
            ? (((size_t)(bb * 16 + hh)) * 64 + d) * 2048 + l
            : (((size_t)(bb * 16 + hh)) * 2048 + l) * 64 + d;
        Y[idx] = f2bf(val);
      }
  }
}

// ---- flash attention: u=2 q-frags x split-K 2 (round-14 proven core) ----
__global__ __launch_bounds__(256) void attn_kernel(
    const u16* __restrict__ ws, const int* __restrict__ mask,
    float* __restrict__ out, float* __restrict__ part1, float* __restrict__ pl) {
  __shared__ u16 klds[4096];        // [key][chunk^(key&7)] 64x64
  __shared__ u16 vtlds[4096];       // [d][chunk^(d&7)] 64x64 (V^T)
  __shared__ u16 pt[4][2][16][72];  // per-wave, per-u P^T; 144B rows (16B multiple: b128-safe)

  const int bh = blockIdx.y, b = bh >> 4, h = bh & 15;
  const int qbase = blockIdx.x * 128;
  const int half = blockIdx.z;
  const int koff = half << 10;
  float* po = half ? part1 : out;
  float* plh = pl + half * 65536;   // [half][bh][2048]

  const u16* qp = ws + (size_t)bh * 131072;
  const u16* kp = ws + 4194304 + (size_t)bh * 131072;
  const u16* vp = ws + 8388608 + (size_t)bh * 131072;  // [64 d][2048 l]
  const int* maskrow = mask + (h & 1) * 2048;          // torch-tile quirk: batch idx = h%2

  const int tid = threadIdx.x;
  const int w = tid >> 6, ln = tid & 63, g = ln >> 4, q16 = ln & 15;
  const int x7 = q16 & 7;

  // Q as B-operand: 2 q-frags per wave (wave covers 32 q-rows)
  u16x8 qf[2][2];
  #pragma unroll
  for (int u = 0; u < 2; ++u)
    #pragma unroll
    for (int s = 0; s < 2; ++s)
      qf[u][s] = *(const u16x8*)(qp + (size_t)(qbase + w * 32 + u * 16 + q16) * 64 + s * 32 + g * 8);

  const int srow = w * 8 + (ln >> 3);
  const int sch = (ln & 7) ^ (ln >> 3);
  const u16* kg = kp + (size_t)srow * 64 + sch * 8;
  const u16* vg = vp + (size_t)srow * 2048 + sch * 8;

  float l_[2] = { 0.f, 0.f };   // per-lane per-u PARTIAL denominators
  f32x4 ov[2][4] = {};          // O^T partials

  for (int kt = koff; kt < koff + 1024; kt += 64) {
    __syncthreads();
    gload16(kg + (size_t)kt * 64, klds + w * 512);
    gload16(kg + (size_t)kt * 64 + 2048, klds + w * 512 + 2048);
    gload16(vg + kt, vtlds + w * 512);
    gload16(vg + kt + 65536, vtlds + w * 512 + 2048);
    const unsigned long long bal = __ballot(maskrow[kt + ln] != 0);
    __syncthreads();

    f32x4 sf[2][4];
    #pragma unroll
    for (int f = 0; f < 4; ++f) {
      u16x8 kf0 = *(const u16x8*)&klds[(f * 16 + q16) * 64 + (g ^ x7) * 8];
      u16x8 kf1 = *(const u16x8*)&klds[(f * 16 + q16) * 64 + ((4 + g) ^ x7) * 8];
      #pragma unroll
      for (int u = 0; u < 2; ++u) {
        f32x4 s = { 0.f, 0.f, 0.f, 0.f };
        mfma32(s, kf0, qf[u][0]);
        mfma32(s, kf1, qf[u][1]);
        sf[u][f] = s;
      }
    }
    {
      const u32 blo = (u32)bal, bhi = (u32)(bal >> 32);
      #pragma unroll
      for (int f = 0; f < 4; ++f) {
        const u32 nib = (((f & 2) ? bhi : blo) >> (16 * (f & 1) + 4 * g)) & 15u;
        #pragma unroll
        for (int r2 = 0; r2 < 4; ++r2)
          if (!((nib >> r2) & 1u)) { sf[0][f][r2] = -1e9f; sf[1][f][r2] = -1e9f; }
      }
    }

    // no-max softmax: p = 2^(S'); masked -> exact 0; l accumulates linearly
    #pragma unroll
    for (int u = 0; u < 2; ++u) {
      #pragma unroll
      for (int f = 0; f < 4; ++f)
        #pragma unroll
        for (int r2 = 0; r2 < 4; ++r2)
          sf[u][f][r2] = ex2(sf[u][f][r2]);
      l_[u] += ((sf[u][0][0] + sf[u][0][1]) + (sf[u][0][2] + sf[u][0][3])) +
               ((sf[u][1][0] + sf[u][1][1]) + (sf[u][1][2] + sf[u][1][3])) +
               ((sf[u][2][0] + sf[u][2][1]) + (sf[u][2][2] + sf[u][2][3])) +
               ((sf[u][3][0] + sf[u][3][1]) + (sf[u][3][2] + sf[u][3][3]));

      #pragma unroll
      for (int f = 0; f < 4; ++f) {
        u32x2 pw = { pk2(sf[u][f][0], sf[u][f][1]), pk2(sf[u][f][2], sf[u][f][3]) };
        *(u16x4*)&pt[w][u][q16][f * 16 + 4 * g] = __builtin_bit_cast(u16x4, pw);
      }
    }
    asm volatile("s_waitcnt lgkmcnt(0)" ::: "memory");
    u16x8 pa0[2], pa1[2];
    #pragma unroll
    for (int u = 0; u < 2; ++u) {
      pa0[u] = *(const u16x8*)&pt[w][u][q16][g * 8];
      pa1[u] = *(const u16x8*)&pt[w][u][q16][32 + g * 8];
    }
    asm volatile("" ::: "memory");

    // O^T += V^T @ P : vf fragments shared across both u (the DS amortization)
    #pragma unroll
    for (int dc = 0; dc < 4; ++dc) {
      u16x8 vf0 = *(const u16x8*)&vtlds[(dc * 16 + q16) * 64 + (g ^ x7) * 8];
      u16x8 vf1 = *(const u16x8*)&vtlds[(dc * 16 + q16) * 64 + ((4 + g) ^ x7) * 8];
      #pragma unroll
      for (int u = 0; u < 2; ++u) {
        mfma32(ov[u][dc], vf0, pa0[u]);
        mfma32(ov[u][dc], vf1, pa1[u]);
      }
    }
  }

  // epilogue: reduce partial l_ per u; store UN-normalized partials
  #pragma unroll
  for (int u = 0; u < 2; ++u) {
    l_[u] += __shfl_xor(l_[u], 16);
    l_[u] += __shfl_xor(l_[u], 32);
    const int qrow = qbase + w * 32 + u * 16 + q16;
    if ((ln & 48) == 0) plh[bh * 2048 + qrow] = l_[u];
    #pragma unroll
    for (int dc = 0; dc < 4; ++dc) {
      float4 o4 = { ov[u][dc][0], ov[u][dc][1], ov[u][dc][2], ov[u][dc][3] };
      *(float4*)&po[((size_t)(b * 2048 + qrow)) * 1024 + h * 64 + dc * 16 + 4 * g] = o4;
    }
  }
}

// ---- combine: out = (out + part1) / (l0 + l1), elementwise float4 ----
__global__ __launch_bounds__(256) void combine_kernel(
    float* __restrict__ out, const float* __restrict__ part1, const float* __restrict__ pl) {
  const int e = blockIdx.x * 256 + threadIdx.x;   // float4 index
  const int i = e * 4;
  const int b = i >> 21;            // / (2048*1024)
  const int rem = i & 2097151;
  const int q = rem >> 10;
  const int c = rem & 1023;
  const int h = c >> 6;
  const int bhq = ((b * 16 + h) << 11) + q;
  const float rinv = 1.0f / (pl[bhq] + pl[65536 + bhq]);
  float4 a = *(const float4*)&out[i];
  float4 p = *(const float4*)&part1[i];
  float4 r = { (a.x + p.x) * rinv, (a.y + p.y) * rinv, (a.z + p.z) * rinv, (a.w + p.w) * rinv };
  *(float4*)&out[i] = r;
}

extern "C" void kernel_launch(void* const* d_in, const int* in_sizes, int n_in,
                              void* d_out, int out_size, void* d_ws, size_t ws_size,
                              hipStream_t stream) {
  const float* Qin = (const float*)d_in[0];
  const float* Kin = (const float*)d_in[1];
  const float* Vin = (const float*)d_in[2];
  const int* mask = (const int*)d_in[3];
  const float* WQ = (const float*)d_in[4];
  const float* bQ = (const float*)d_in[5];
  const float* WK = (const float*)d_in[6];
  const float* WV = (const float*)d_in[7];
  const float* bV = (const float*)d_in[8];
  float* out = (float*)d_out;
  u16* ws = (u16*)d_ws;

  // ws layout (u16): [0) qkv 3x4194304 | [12582912) Xb (reused as part1+pl after proj) | [25165824) Wt
  float* part1 = (float*)(ws + 12582912);             // 16.7 MB
  float* pl = (float*)(ws + 12582912 + 8388608);      // 0.5 MB

  const bool fast = ws_size >= (size_t)56623104;
  if (fast) {
    convX<<<dim3(4096, 3), 256, 0, stream>>>(Qin, Kin, Vin, ws + 12582912);
    convW<<<dim3(128, 4, 3), 256, 0, stream>>>(WQ, WK, WV, ws + 25165824);
    proj_fast<<<dim3(8, 32, 3), 256, 0, stream>>>(ws + 12582912, ws + 25165824, bQ, bV, ws);
  } else {
    proj_legacy<<<dim3(8, 32, 3), 256, 0, stream>>>(Qin, Kin, Vin, WQ, WK, WV, bQ, bV, ws);
  }
  attn_kernel<<<dim3(16, 32, 2), 256, 0, stream>>>(ws, mask, out, part1, pl);
  combine_kernel<<<4096, 256, 0, stream>>>(out, part1, pl);
}